// Round 10
// baseline (636.547 us; speedup 1.0000x reference)
//
#include <hip/hip_runtime.h>
#include <cstdint>
#include <type_traits>

typedef uint16_t u16;
typedef uint32_t u32;
typedef __attribute__((ext_vector_type(4))) float f32x4;
typedef __attribute__((ext_vector_type(8))) __bf16 vbf8;
typedef __attribute__((ext_vector_type(8))) short vs8;

// ---- MFMA operand-type hedge: prefer v8bf16, fall back to v8i16 ----
template <typename T, typename = void>
struct CanMfma : std::false_type {};
template <typename T>
struct CanMfma<T, std::void_t<decltype(__builtin_amdgcn_mfma_f32_16x16x32_bf16(
    std::declval<T>(), std::declval<T>(), std::declval<f32x4>(), 0, 0, 0))>>
    : std::true_type {};
typedef std::conditional_t<CanMfma<vbf8>::value, vbf8, vs8> frag_t;

__device__ __forceinline__ f32x4 mfma_bf16(frag_t a, frag_t b, f32x4 c) {
  return __builtin_amdgcn_mfma_f32_16x16x32_bf16(a, b, c, 0, 0, 0);
}

__device__ __forceinline__ u16 f2bf(float f) {
  u32 u = __builtin_bit_cast(u32, f);
  u32 r = (u + 0x7FFFu + ((u >> 16) & 1u)) >> 16;
  return (u16)r;
}

// 8x f32 -> bf16 fragment (RNE). Template so the discarded constexpr branch is
// never instantiated (fixes R9 compile error). vbf8 path: plain casts -> compiler
// emits v_cvt_pk_bf16_f32 pairs (m240: hand-written asm cvt_pk is slower).
template <typename FT = frag_t>
__device__ __forceinline__ FT cvt8_bf16(float4 lo, float4 hi) {
  if constexpr (std::is_same<FT, vbf8>::value) {
    vbf8 f;
    f[0] = (__bf16)lo.x; f[1] = (__bf16)lo.y;
    f[2] = (__bf16)lo.z; f[3] = (__bf16)lo.w;
    f[4] = (__bf16)hi.x; f[5] = (__bf16)hi.y;
    f[6] = (__bf16)hi.z; f[7] = (__bf16)hi.w;
    return f;
  } else {
    union { FT v; u16 e[8]; } f;
    f.e[0] = f2bf(lo.x); f.e[1] = f2bf(lo.y);
    f.e[2] = f2bf(lo.z); f.e[3] = f2bf(lo.w);
    f.e[4] = f2bf(hi.x); f.e[5] = f2bf(hi.y);
    f.e[6] = f2bf(hi.z); f.e[7] = f2bf(hi.w);
    return f.v;
  }
}

__device__ __forceinline__ void gload_lds16(const void* g, void* l) {
  __builtin_amdgcn_global_load_lds(
      (const __attribute__((address_space(1))) void*)g,
      (__attribute__((address_space(3))) void*)l, 16, 0, 0);
}

// ---------------- cast fp32 -> bf16 (only for p now) ----------------
__global__ __launch_bounds__(256) void cast_f32_bf16(
    const float* __restrict__ in, u16* __restrict__ out, int n8) {
  int i = blockIdx.x * 256 + threadIdx.x;
  const int stride = gridDim.x * 256;
  for (; i < n8; i += stride) {
    const float4 a  = ((const float4*)in)[(size_t)i * 2];
    const float4 b2 = ((const float4*)in)[(size_t)i * 2 + 1];
    uint4 o;
    o.x = (u32)f2bf(a.x)  | ((u32)f2bf(a.y)  << 16);
    o.y = (u32)f2bf(a.z)  | ((u32)f2bf(a.w)  << 16);
    o.z = (u32)f2bf(b2.x) | ((u32)f2bf(b2.y) << 16);
    o.w = (u32)f2bf(b2.z) | ((u32)f2bf(b2.w) << 16);
    ((uint4*)out)[(size_t)i] = o;
  }
}

// ---------------- transpose + cast: in[K][N] f32 -> out[N][K] bf16 ----------------
__global__ __launch_bounds__(256) void transpose_cast(
    const float* __restrict__ in, u16* __restrict__ out, int K, int N) {
  __shared__ float tile[32][33];
  const int k0 = blockIdx.x * 32, n0 = blockIdx.y * 32;
  const int tr = threadIdx.x >> 5, tc = threadIdx.x & 31;
#pragma unroll
  for (int i = 0; i < 4; ++i)
    tile[tr + i * 8][tc] = in[(size_t)(k0 + tr + i * 8) * N + (n0 + tc)];
  __syncthreads();
#pragma unroll
  for (int i = 0; i < 4; ++i)
    out[(size_t)(n0 + tr + i * 8) * K + (k0 + tc)] = f2bf(tile[tc][tr + i * 8]);
}

// ---------------- small GEMM (128^2, 2-phase dbuf) for K/V projections ----------------
template <bool OUT_BF16>
__global__ __launch_bounds__(256) void gemm_bt(
    const u16* __restrict__ A, const u16* __restrict__ Bt,
    const float* __restrict__ bias, void* __restrict__ Cout,
    int M, int N, int K, int Mtiles, int Ntiles) {
  __shared__ char Al[2][128 * 32 * 2];
  __shared__ char Bl[2][128 * 32 * 2];

  const int nwg = Mtiles * Ntiles;
  int bid = (int)blockIdx.x;
  bid = (bid & 7) * (nwg >> 3) + (bid >> 3);
  const int mt = bid / Ntiles, nt = bid % Ntiles;
  const int m0 = mt * 128, n0 = nt * 128;

  const int tid = (int)threadIdx.x;
  const int lane = tid & 63;
  const int wv = tid >> 6;
  const int wm = wv & 1, wn = wv >> 1;
  const int lr = lane & 15, lg = lane >> 4;
  const int rsub = lane >> 2;
  const int slot = lane & 3;
  const int rb0 = n0 + rsub;

  auto stage = [&](int buf, int t) {
    const int k0 = t << 5;
#pragma unroll
    for (int c = 0; c < 2; ++c) {
      const int ci = c * 4 + wv;
      int rra = m0 + ci * 16 + rsub;
      if (rra >= M) rra = M - 1;
      gload_lds16(A + (size_t)rra * K + k0 + slot * 8, Al[buf] + ci * 1024);
      const int rrb = rb0 + ci * 16;
      gload_lds16(Bt + (size_t)rrb * K + k0 + slot * 8, Bl[buf] + ci * 1024);
    }
  };

  f32x4 zero4 = {0.f, 0.f, 0.f, 0.f};
  f32x4 acc[4][4];
#pragma unroll
  for (int i = 0; i < 4; ++i)
#pragma unroll
    for (int j = 0; j < 4; ++j) acc[i][j] = zero4;

  const int nk = K >> 5;
  int cur = 0;
  stage(0, 0);
  __syncthreads();

  for (int t = 0; t < nk; ++t) {
    if (t + 1 < nk) stage(cur ^ 1, t + 1);
    frag_t af[4], bf[4];
#pragma unroll
    for (int i = 0; i < 4; ++i) {
      af[i] = *(const frag_t*)(Al[cur] + (wm * 64 + i * 16 + lr) * 64 + lg * 16);
      bf[i] = *(const frag_t*)(Bl[cur] + (wn * 64 + i * 16 + lr) * 64 + lg * 16);
    }
#pragma unroll
    for (int i = 0; i < 4; ++i)
#pragma unroll
      for (int j = 0; j < 4; ++j)
        acc[i][j] = mfma_bf16(af[i], bf[j], acc[i][j]);
    __syncthreads();
    cur ^= 1;
  }

#pragma unroll
  for (int j = 0; j < 4; ++j) {
    const int col = n0 + wn * 64 + j * 16 + lr;
    const float bv = bias[col];
#pragma unroll
    for (int i = 0; i < 4; ++i) {
      const int rbase = m0 + wm * 64 + i * 16 + lg * 4;
#pragma unroll
      for (int r = 0; r < 4; ++r) {
        const int row = rbase + r;
        const float val = acc[i][j][r] + bv;
        if constexpr (OUT_BF16) {
          u32 me = f2bf(val);
          u32 other = __shfl_xor(me, 1);
          if ((lane & 1) == 0 && row < M) {
            *(u32*)((u16*)Cout + (size_t)row * N + col) = me | (other << 16);
          }
        } else {
          if (row < M) ((float*)Cout)[(size_t)row * N + col] = val;
        }
      }
    }
  }
}

// ---------------- big GEMM: 256x128 tile, BK=32, 2-phase, 2 blocks/CU ----------------
// R7-proven sync structure unchanged. A_F32=true: A staged as raw fp32 via
// global_load_lds (no cast kernel, no ds_write in loop); fragments read as 2x
// ds_read_b128 + in-register cvt. LDS: A 32KB(f32)/16KB(bf16) + B 8KB, x2 dbuf
// = 80/48 KB -> still 2 blocks/CU. Swizzles: A-f32 rows 128B/8slots phys=log^(row&7);
// A-bf16 & B rows 64B/4slots phys=log^((row>>1)&3). Sources pre-swizzled (rule 21).
template <bool OUT_BF16, bool A_F32>
__global__ __launch_bounds__(512, 4) void gemm256(
    const void* __restrict__ Ain, const u16* __restrict__ Bt,
    const float* __restrict__ bias, void* __restrict__ Cout,
    int M, int N, int K) {
  constexpr int AHALF = A_F32 ? 16384 : 8192;  // u16 units per A buffer
  __shared__ u16 Al[2][AHALF];
  __shared__ u16 Bl[2][128 * 32];

  const u16* A16 = (const u16*)Ain;
  const float* A32 = (const float*)Ain;

  const int Ntiles = N >> 7;
  const int nwg = (M >> 8) * Ntiles;
  int bid = (int)blockIdx.x;
  bid = (bid & 7) * (nwg >> 3) + (bid >> 3);  // bijective: nwg % 8 == 0
  const int mt = bid / Ntiles, ntl = bid % Ntiles;
  const int m0 = mt << 8, n0 = ntl << 7;

  const int tid = (int)threadIdx.x;
  const int lane = tid & 63;
  const int wid = tid >> 6;
  const int wm = wid >> 1, wn = wid & 1;  // 4 x 2 wave grid, per-wave 64x64
  const int lr = lane & 15, lg = lane >> 4;

  // B staging (common): 16 rows x 64B per gload; src slot pre-swizzled.
  const u16* Bbase = Bt + (size_t)(n0 + wid * 16 + (lane >> 2)) * K +
                     ((lane & 3) ^ ((lane >> 3) & 3)) * 8;
  // A staging bases
  const u16* Abase16 =
      A_F32 ? nullptr
            : A16 + (size_t)(m0 + wid * 32 + (lane >> 2)) * K +
                  ((lane & 3) ^ ((lane >> 3) & 3)) * 8;
  const float* Abase32 =
      A_F32 ? A32 + (size_t)(m0 + wid * 32 + (lane >> 3)) * K +
                  ((lane & 7) ^ (lane >> 3)) * 4
            : nullptr;

  auto stage = [&](u16* da, u16* db, int t) {
    const int k0 = t << 5;
    if constexpr (A_F32) {
      const float* g = Abase32 + k0;
      char* l = (char*)da + wid * 4096;  // 32 rows * 128 B per wave
      gload_lds16(g, l);
      gload_lds16(g + ((size_t)K << 3), l + 1024);   // +8 rows
      gload_lds16(g + ((size_t)K << 4), l + 2048);   // +16 rows
      gload_lds16(g + (size_t)K * 24, l + 3072);     // +24 rows
    } else {
      gload_lds16(Abase16 + k0, (char*)da + wid * 2048);
      gload_lds16(Abase16 + ((size_t)K << 4) + k0, (char*)da + wid * 2048 + 1024);
    }
    gload_lds16(Bbase + k0, (char*)db + wid * 1024);
  };

  auto ldsB = [&](const u16* base, int row) -> frag_t {
    const int phys = lg ^ ((row >> 1) & 3);
    return *(const frag_t*)(base + (size_t)row * 32 + phys * 8);
  };
  auto ldsA = [&](const u16* base, int row) -> frag_t {
    if constexpr (A_F32) {
      const float* bp = (const float*)base;
      const int s0 = (2 * lg) ^ (row & 7);
      const int s1 = (2 * lg + 1) ^ (row & 7);
      float4 lo = *(const float4*)(bp + (size_t)row * 32 + s0 * 4);
      float4 hi = *(const float4*)(bp + (size_t)row * 32 + s1 * 4);
      return cvt8_bf16(lo, hi);
    } else {
      const int phys = lg ^ ((row >> 1) & 3);
      return *(const frag_t*)(base + (size_t)row * 32 + phys * 8);
    }
  };

  f32x4 zero4 = {0.f, 0.f, 0.f, 0.f};
  f32x4 acc[4][4];
#pragma unroll
  for (int i = 0; i < 4; ++i)
#pragma unroll
    for (int j = 0; j < 4; ++j) acc[i][j] = zero4;

  const int nt = K >> 5;  // K-tiles, >= 2
  const int ar0 = wm * 64 + lr;
  const int br0 = wn * 64 + lr;

  // prologue: stage tiles 0 and 1; wait tile 0 only (tile 1 stays in flight)
  stage(&Al[0][0], &Bl[0][0], 0);
  stage(&Al[1][0], &Bl[1][0], 1);
  if constexpr (A_F32)
    asm volatile("s_waitcnt vmcnt(5)" ::: "memory");
  else
    asm volatile("s_waitcnt vmcnt(3)" ::: "memory");
  __builtin_amdgcn_s_barrier();

  for (int t = 0; t < nt; ++t) {
    const int cur = t & 1;
    const u16* al = &Al[cur][0];
    const u16* bl = &Bl[cur][0];
    // stage tile t+1 into the buffer consumed at t-1 (read done, barrier passed)
    if (t >= 1 && t + 1 < nt)
      stage(&Al[cur ^ 1][0], &Bl[cur ^ 1][0], t + 1);
    // single scheduling region: ds_reads (+cvt on f32 path) + 16 MFMA
    frag_t a[4], b[4];
#pragma unroll
    for (int i = 0; i < 4; ++i) a[i] = ldsA(al, ar0 + i * 16);
#pragma unroll
    for (int j = 0; j < 4; ++j) b[j] = ldsB(bl, br0 + j * 16);
#pragma unroll
    for (int i = 0; i < 4; ++i)
#pragma unroll
      for (int j = 0; j < 4; ++j)
        acc[i][j] = mfma_bf16(a[i], b[j], acc[i][j]);
    if (t + 1 < nt) {
      asm volatile("s_waitcnt vmcnt(0)" ::: "memory");
      __builtin_amdgcn_s_barrier();
    }
  }

  // epilogue: row = m0+wm*64+ai*16+lg*4+rr ; col = n0+wn*64+bj*16+lr
  float bvv[4];
#pragma unroll
  for (int bj = 0; bj < 4; ++bj) bvv[bj] = bias[n0 + wn * 64 + bj * 16 + lr];
#pragma unroll
  for (int ai = 0; ai < 4; ++ai) {
    const int rbase = m0 + wm * 64 + ai * 16 + lg * 4;
#pragma unroll
    for (int rr = 0; rr < 4; ++rr) {
      const int row = rbase + rr;
#pragma unroll
      for (int bj = 0; bj < 4; ++bj) {
        const int cb = n0 + wn * 64 + bj * 16;
        const float val = acc[ai][bj][rr] + bvv[bj];
        if constexpr (OUT_BF16) {
          u32 me = f2bf(val);
          u32 d0 = me | (__shfl_xor(me, 1) << 16);
          u32 d1 = __shfl_xor(d0, 2);
          if ((lane & 3) == 0) {
            uint2 o; o.x = d0; o.y = d1;
            *(uint2*)((u16*)Cout + (size_t)row * N + cb + (lr & 12)) = o;
          }
        } else {
          float v0 = val;
          float v1 = __shfl_xor(v0, 1);
          float v2 = __shfl_xor(v0, 2);
          float v3 = __shfl_xor(v1, 2);
          if ((lane & 3) == 0) {
            float4 o; o.x = v0; o.y = v1; o.z = v2; o.w = v3;
            *(float4*)((float*)Cout + (size_t)row * N + cb + (lr & 12)) = o;
          }
        }
      }
    }
  }
}

// ---------------- attention (unchanged, passing) ----------------
__global__ __launch_bounds__(256) void attn_kernel(
    const u16* __restrict__ Q, const u16* __restrict__ K,
    const u16* __restrict__ V, u16* __restrict__ O) {
  __shared__ u16 Kl[96][72];
  __shared__ u16 Vt[64][104];

  const int bid = blockIdx.x;
  const int qt = bid & 63;
  const int h = (bid >> 6) & 15;
  const int b = bid >> 10;
  const int tid = threadIdx.x;

#pragma unroll
  for (int it = 0; it < 3; ++it) {
    const int idx = tid + it * 256;
    const int key = idx >> 3, s = idx & 7;
    uint4 val{0u, 0u, 0u, 0u};
    if (key < 77)
      val = *(const uint4*)(K + ((size_t)(b * 77 + key)) * 1024 + h * 64 + s * 8);
    *(uint4*)(&Kl[key][s * 8]) = val;
  }
#pragma unroll
  for (int it = 0; it < 3; ++it) {
    const int idx = tid + it * 256;
    if (idx < 616) {
      const int key = idx >> 3, s = idx & 7;
      const uint4 v4 =
          *(const uint4*)(V + ((size_t)(b * 77 + key)) * 1024 + h * 64 + s * 8);
      const u16* e = (const u16*)&v4;
#pragma unroll
      for (int j = 0; j < 8; ++j) Vt[s * 8 + j][key] = e[j];
    }
  }
#pragma unroll
  for (int it = 0; it < 5; ++it) {
    const int idx = tid + it * 256;
    if (idx < 1216) {
      const int d = idx / 19, kk = 77 + idx % 19;
      Vt[d][kk] = 0;
    }
  }
  __syncthreads();

  const int lane = tid & 63;
  const int wv = tid >> 6;
  const int lr = lane & 15;
  const int lg = lane >> 4;

  const size_t qrow = (size_t)(b * 4096 + qt * 64 + wv * 16 + lr) * 1024 + h * 64;
  frag_t qf[2];
#pragma unroll
  for (int ks = 0; ks < 2; ++ks)
    qf[ks] = *(const frag_t*)(Q + qrow + ks * 32 + lg * 8);

  f32x4 zero4 = {0.f, 0.f, 0.f, 0.f};
  f32x4 sa[5] = {zero4, zero4, zero4, zero4, zero4};
#pragma unroll
  for (int ks = 0; ks < 2; ++ks) {
#pragma unroll
    for (int kt = 0; kt < 5; ++kt) {
      frag_t kf = *(const frag_t*)(&Kl[kt * 16 + lr][ks * 32 + lg * 8]);
      sa[kt] = mfma_bf16(kf, qf[ks], sa[kt]);
    }
  }

  float p[5][4];
  float mx = -3.0e38f;
#pragma unroll
  for (int kt = 0; kt < 5; ++kt)
#pragma unroll
    for (int r = 0; r < 4; ++r) {
      const int key = kt * 16 + lg * 4 + r;
      float s = sa[kt][r] * 0.125f;
      if (key >= 77) s = -3.0e38f;
      p[kt][r] = s;
      mx = fmaxf(mx, s);
    }
  mx = fmaxf(mx, __shfl_xor(mx, 16));
  mx = fmaxf(mx, __shfl_xor(mx, 32));
  float sum = 0.f;
#pragma unroll
  for (int kt = 0; kt < 5; ++kt)
#pragma unroll
    for (int r = 0; r < 4; ++r) {
      const float e = __expf(p[kt][r] - mx);
      p[kt][r] = e;
      sum += e;
    }
  sum += __shfl_xor(sum, 16);
  sum += __shfl_xor(sum, 32);
  const float rden = 1.0f / sum;
#pragma unroll
  for (int kt = 0; kt < 5; ++kt)
#pragma unroll
    for (int r = 0; r < 4; ++r) p[kt][r] *= rden;

  union FP { frag_t v; u16 e[8]; };
  frag_t pa[3];
#pragma unroll
  for (int kb = 0; kb < 3; ++kb) {
    FP f;
#pragma unroll
    for (int j = 0; j < 8; ++j) {
      const int kt = 2 * kb + (j >> 2);
      f.e[j] = (kt < 5) ? f2bf(p[kt][j & 3]) : (u16)0;
    }
    pa[kb] = f.v;
  }

  f32x4 oa[4] = {zero4, zero4, zero4, zero4};
#pragma unroll
  for (int nt = 0; nt < 4; ++nt) {
    const int d = nt * 16 + lr;
#pragma unroll
    for (int kb = 0; kb < 3; ++kb) {
      const int key0 = kb * 32 + lg * 4;
      FP vb;
      *(uint2*)(&vb.e[0]) = *(const uint2*)(&Vt[d][key0]);
      *(uint2*)(&vb.e[4]) = *(const uint2*)(&Vt[d][key0 + 16]);
      oa[nt] = mfma_bf16(pa[kb], vb.v, oa[nt]);
    }
  }

#pragma unroll
  for (int nt = 0; nt < 4; ++nt)
#pragma unroll
    for (int r = 0; r < 4; ++r) {
      const int qr = wv * 16 + lg * 4 + r;
      u32 me = f2bf(oa[nt][r]);
      u32 other = __shfl_xor(me, 1);
      if ((lane & 1) == 0) {
        *(u32*)(O + ((size_t)(b * 4096 + qt * 64 + qr)) * 1024 + h * 64 +
                nt * 16 + lr) = me | (other << 16);
      }
    }
}

// ---------------- launch ----------------
extern "C" void kernel_launch(void* const* d_in, const int* in_sizes, int n_in,
                              void* d_out, int out_size, void* d_ws, size_t ws_size,
                              hipStream_t stream) {
  const float* x  = (const float*)d_in[0];
  const float* p  = (const float*)d_in[1];
  const float* Wq = (const float*)d_in[2];
  const float* bq = (const float*)d_in[3];
  const float* Wk = (const float*)d_in[4];
  const float* bk = (const float*)d_in[5];
  const float* Wv = (const float*)d_in[6];
  const float* bv = (const float*)d_in[7];
  const float* Ww = (const float*)d_in[8];
  const float* bw = (const float*)d_in[9];

  char* ws = (char*)d_ws;
  if (ws_size < 281034752ULL) return;

  u16* ao_bf = (u16*)(ws + 0);         // 65536x1024 bf16 attention output
  u16* q_bf = (u16*)(ws + 134217728);  // 65536x1024
  u16* wq_t = (u16*)(ws + 268435456);  // [1024][1024]
  u16* ww_t = (u16*)(ws + 270532608);  // [1024][1024]
  u16* wk_t = (u16*)(ws + 272629760);  // [1024][512]
  u16* wv_t = (u16*)(ws + 273678336);  // [1024][512]
  u16* p_bf = (u16*)(ws + 274726912);  // 1232x512
  u16* k_bf = (u16*)(ws + 275988480);  // 1232x1024
  u16* v_bf = (u16*)(ws + 278511616);  // 1232x1024

  cast_f32_bf16<<<308, 256, 0, stream>>>(p, p_bf, 78848);
  transpose_cast<<<dim3(32, 32), 256, 0, stream>>>(Wq, wq_t, 1024, 1024);
  transpose_cast<<<dim3(32, 32), 256, 0, stream>>>(Ww, ww_t, 1024, 1024);
  transpose_cast<<<dim3(16, 32), 256, 0, stream>>>(Wk, wk_t, 512, 1024);
  transpose_cast<<<dim3(16, 32), 256, 0, stream>>>(Wv, wv_t, 512, 1024);

  // K/V projections (small): 2-phase 128^2 kernel
  gemm_bt<true><<<80, 256, 0, stream>>>(p_bf, wk_t, bk, k_bf, 1232, 1024, 512, 10, 8);
  gemm_bt<true><<<80, 256, 0, stream>>>(p_bf, wv_t, bv, v_bf, 1232, 1024, 512, 10, 8);
  // Q projection: fused fp32-A via global_load_lds (no standalone x cast)
  gemm256<true, true><<<2048, 512, 0, stream>>>(x, wq_t, bq, q_bf, 65536, 1024, 1024);
  // attention
  attn_kernel<<<16384, 256, 0, stream>>>(q_bf, k_bf, v_bf, ao_bf);
  // out projection -> fp32 (A = attn output, bf16 gload path)
  gemm256<false, false><<<2048, 512, 0, stream>>>(ao_bf, ww_t, bw, d_out,
                                                  65536, 1024, 1024);
}